// Round 1
// baseline (577.947 us; speedup 1.0000x reference)
//
#include <hip/hip_runtime.h>

typedef unsigned short u16;
typedef __bf16 bf16x8 __attribute__((ext_vector_type(8)));
typedef float f32x4 __attribute__((ext_vector_type(4)));

// ---------- helpers ----------
__device__ __forceinline__ u16 f2bf(float f) {
  unsigned u = __builtin_bit_cast(unsigned, f);
  return (u16)((u + 0x7fffu + ((u >> 16) & 1u)) >> 16);
}

__device__ __forceinline__ void async_load16(const void* g, void* l) {
  __builtin_amdgcn_global_load_lds((const __attribute__((address_space(1))) void*)g,
                                   (__attribute__((address_space(3))) void*)l,
                                   16, 0, 0);
}

// ---------- pad + cast x: (1024,784) f32 -> (1024,800) bf16 ----------
__global__ void pad_x_k(const float* __restrict__ x, u16* __restrict__ xbf) {
  int idx = blockIdx.x * 256 + threadIdx.x;          // 1024*800
  int m = idx / 800, k = idx - m * 800;
  float v = (k < 784) ? x[m * 784 + k] : 0.f;
  xbf[idx] = f2bf(v);
}

// ---------- sample W and transpose to Wt[s][n][k] bf16 (K padded to Kp) ----------
__global__ void sample_w_k(const float* __restrict__ we,   // chunk base: (SC,K,N)
                           const float* __restrict__ wm,   // (K,N)
                           const float* __restrict__ wv,   // (K,N)
                           u16* __restrict__ wt,           // (SC,N,Kp)
                           int K, int N, int Kp) {
  __shared__ float tile[32][33];
  int s = blockIdx.z;
  int k0 = blockIdx.x * 32, n0 = blockIdx.y * 32;
  int tx = threadIdx.x, ty = threadIdx.y;              // block (32,8)
  const float* we_s = we + (size_t)s * K * N;
#pragma unroll
  for (int r = ty; r < 32; r += 8) {
    int k = k0 + r, n = n0 + tx;
    float v = 0.f;
    if (k < K) {
      size_t idx = (size_t)k * N + n;
      v = fmaf(__expf(0.5f * wv[idx]), we_s[idx], wm[idx]);
    }
    tile[r][tx] = v;
  }
  __syncthreads();
  u16* wt_s = wt + (size_t)s * N * Kp;
#pragma unroll
  for (int r = ty; r < 32; r += 8) {
    int n = n0 + r, k = k0 + tx;
    wt_s[(size_t)n * Kp + k] = f2bf(tile[tx][r]);
  }
}

// ---------- sample last-layer W -> Wlt[s][16][1024] bf16 (n>=10 zero) ----------
__global__ void sample_wl_k(const float* __restrict__ wel,  // chunk base (SC,1024,10)
                            const float* __restrict__ wlm,  // (1024,10)
                            const float* __restrict__ wlv,  // (1024,10)
                            u16* __restrict__ wlt) {        // (SC,16,1024)
  int idx = blockIdx.x * 256 + threadIdx.x;   // SC*16*1024
  int k = idx & 1023;
  int n = (idx >> 10) & 15;
  int s = idx >> 14;
  float v = 0.f;
  if (n < 10) {
    size_t i2 = ((size_t)s * 1024 + k) * 10 + n;
    size_t iw = (size_t)k * 10 + n;
    v = fmaf(__expf(0.5f * wlv[iw]), wel[i2], wlm[iw]);
  }
  wlt[idx] = f2bf(v);
}

// ---------- batched GEMM: C[s] = relu(A[s] @ Bt[s]^T + bias[s]) ----------
// A: (M=1024, K) bf16 row-major (strideAs==0 -> shared A), Bt: (N=1024, K) bf16
// C: (1024,1024) bf16. bias_n = bm[n] + exp(0.5*bv[n]) * be[sg*1024+n]
__global__ __launch_bounds__(256) void gemm_bt_relu(
    const u16* __restrict__ A, size_t strideAs, int ldA,
    const u16* __restrict__ Bt,
    u16* __restrict__ C,
    int K,
    const float* __restrict__ bm, const float* __restrict__ bv,
    const float* __restrict__ be, int s_off) {
  __shared__ __align__(16) u16 As[128 * 32];
  __shared__ __align__(16) u16 Bs[128 * 32];

  const int sc = blockIdx.z;
  const int sg = sc + s_off;
  const u16* A_s = A + (size_t)sc * strideAs;
  const u16* B_s = Bt + (size_t)sc * (size_t)1024 * K;
  u16* C_s = C + (size_t)sc * (size_t)1024 * 1024;

  const int m0 = blockIdx.y * 128;
  const int n0 = blockIdx.x * 128;
  const int t = threadIdx.x;
  const int w = t >> 6, l = t & 63;
  const int quad = l >> 4, lane16 = l & 15;
  const int wm_ = (w >> 1) * 64, wn_ = (w & 1) * 64;

  f32x4 acc[4][4];
#pragma unroll
  for (int i = 0; i < 4; ++i)
#pragma unroll
    for (int j = 0; j < 4; ++j) acc[i][j] = (f32x4){0.f, 0.f, 0.f, 0.f};

  for (int k0 = 0; k0 < K; k0 += 32) {
    __syncthreads();  // previous tile's readers done
#pragma unroll
    for (int i = 0; i < 2; ++i) {
      int p = w * 128 + i * 64 + l;                 // 16B chunk id, +l implicit in HW
      const u16* srcA = A_s + (size_t)(m0 + (p >> 2)) * ldA + k0 + (p & 3) * 8;
      async_load16(srcA, &As[(size_t)(w * 128 + i * 64) * 8]);
      const u16* srcB = B_s + (size_t)(n0 + (p >> 2)) * K + k0 + (p & 3) * 8;
      async_load16(srcB, &Bs[(size_t)(w * 128 + i * 64) * 8]);
    }
    __syncthreads();  // staging complete (vmcnt drained by barrier)

    bf16x8 af[4], bfr[4];
#pragma unroll
    for (int mi = 0; mi < 4; ++mi)
      af[mi] = *(const bf16x8*)&As[(wm_ + mi * 16 + lane16) * 32 + quad * 8];
#pragma unroll
    for (int ni = 0; ni < 4; ++ni)
      bfr[ni] = *(const bf16x8*)&Bs[(wn_ + ni * 16 + lane16) * 32 + quad * 8];
#pragma unroll
    for (int mi = 0; mi < 4; ++mi)
#pragma unroll
      for (int ni = 0; ni < 4; ++ni)
        acc[mi][ni] =
            __builtin_amdgcn_mfma_f32_16x16x32_bf16(af[mi], bfr[ni], acc[mi][ni], 0, 0, 0);
  }

  // epilogue: bias (sampled on the fly) + relu + bf16 store
#pragma unroll
  for (int ni = 0; ni < 4; ++ni) {
    int n = n0 + wn_ + ni * 16 + lane16;
    float bias = fmaf(__expf(0.5f * bv[n]), be[(size_t)sg * 1024 + n], bm[n]);
#pragma unroll
    for (int mi = 0; mi < 4; ++mi) {
#pragma unroll
      for (int r = 0; r < 4; ++r) {
        int m = m0 + wm_ + mi * 16 + quad * 4 + r;
        float v = acc[mi][ni][r] + bias;
        v = fmaxf(v, 0.f);
        C_s[(size_t)m * 1024 + n] = f2bf(v);
      }
    }
  }
}

// ---------- final layer: logits[s] = act2[s] @ Wl[s] + bl[s], N=10 ----------
// act2: (SC,1024,1024) bf16 ; Wlt: (SC,16,1024) bf16 ; out: (32,1024,10) f32
__global__ __launch_bounds__(256) void gemm_last_k(
    const u16* __restrict__ act2, const u16* __restrict__ Wlt,
    float* __restrict__ out,
    const float* __restrict__ blm, const float* __restrict__ blv,
    const float* __restrict__ bel, int s_off) {
  const int sc = blockIdx.y;
  const int sg = sc + s_off;
  const int t = threadIdx.x;
  const int w = t >> 6, l = t & 63;
  const int quad = l >> 4, lane16 = l & 15;
  const int m0 = (blockIdx.x * 4 + w) * 16;  // 64 m-tiles per sample

  const u16* A_s = act2 + (size_t)sc * 1024 * 1024;
  const u16* B_s = Wlt + (size_t)sc * 16 * 1024;

  f32x4 acc = (f32x4){0.f, 0.f, 0.f, 0.f};
#pragma unroll 4
  for (int k0 = 0; k0 < 1024; k0 += 32) {
    bf16x8 a = *(const bf16x8*)&A_s[(size_t)(m0 + lane16) * 1024 + k0 + quad * 8];
    bf16x8 b = *(const bf16x8*)&B_s[(size_t)lane16 * 1024 + k0 + quad * 8];
    acc = __builtin_amdgcn_mfma_f32_16x16x32_bf16(a, b, acc, 0, 0, 0);
  }
  int n = lane16;
  if (n < 10) {
    float bias = fmaf(__expf(0.5f * blv[n]), bel[sg * 10 + n], blm[n]);
#pragma unroll
    for (int r = 0; r < 4; ++r) {
      int m = m0 + quad * 4 + r;
      out[((size_t)sg * 1024 + m) * 10 + n] = acc[r] + bias;
    }
  }
}

// ---------- launch ----------
extern "C" void kernel_launch(void* const* d_in, const int* in_sizes, int n_in,
                              void* d_out, int out_size, void* d_ws, size_t ws_size,
                              hipStream_t stream) {
  const float* x   = (const float*)d_in[0];
  const float* wm0 = (const float*)d_in[1];
  const float* wv0 = (const float*)d_in[2];
  const float* bm0 = (const float*)d_in[3];
  const float* bv0 = (const float*)d_in[4];
  const float* wm1 = (const float*)d_in[5];
  const float* wv1 = (const float*)d_in[6];
  const float* bm1 = (const float*)d_in[7];
  const float* bv1 = (const float*)d_in[8];
  const float* wlm = (const float*)d_in[9];
  const float* wlv = (const float*)d_in[10];
  const float* blm = (const float*)d_in[11];
  const float* blv = (const float*)d_in[12];
  const float* we0 = (const float*)d_in[13];
  const float* be0 = (const float*)d_in[14];
  const float* we1 = (const float*)d_in[15];
  const float* be1 = (const float*)d_in[16];
  const float* wel = (const float*)d_in[17];
  const float* bel = (const float*)d_in[18];
  float* out = (float*)d_out;

  // workspace layout (all sizes multiples of 256B)
  const size_t sz_x    = (size_t)1024 * 800 * 2;   // 1,638,400
  const size_t sz_W0t  = (size_t)1024 * 800 * 2;   // per s
  const size_t sz_act  = (size_t)1024 * 1024 * 2;  // per s
  const size_t sz_Wlt  = (size_t)16 * 1024 * 2;    // per s
  const size_t per_s = sz_W0t + 3 * sz_act + sz_Wlt;

  int SC = 32;
  while (SC > 1 && sz_x + (size_t)SC * per_s + 4096 > ws_size) SC >>= 1;

  char* ws = (char*)d_ws;
  size_t off = 0;
  auto take = [&](size_t b) {
    char* p = ws + off;
    off = (off + b + 255) & ~(size_t)255;
    return p;
  };
  u16* xbf  = (u16*)take(sz_x);
  u16* W0t  = (u16*)take((size_t)SC * sz_W0t);
  u16* act1 = (u16*)take((size_t)SC * sz_act);
  u16* W1t  = (u16*)take((size_t)SC * sz_act);
  u16* act2 = (u16*)take((size_t)SC * sz_act);
  u16* Wlt  = (u16*)take((size_t)SC * sz_Wlt);

  pad_x_k<<<3200, 256, 0, stream>>>(x, xbf);

  for (int s0 = 0; s0 < 32; s0 += SC) {
    // layer 0: K=784 (pad 800), N=1024
    sample_w_k<<<dim3(25, 32, SC), dim3(32, 8), 0, stream>>>(
        we0 + (size_t)s0 * 784 * 1024, wm0, wv0, W0t, 784, 1024, 800);
    gemm_bt_relu<<<dim3(8, 8, SC), 256, 0, stream>>>(
        xbf, (size_t)0, 800, W0t, act1, 800, bm0, bv0, be0, s0);
    // layer 1: K=1024, N=1024
    sample_w_k<<<dim3(32, 32, SC), dim3(32, 8), 0, stream>>>(
        we1 + (size_t)s0 * 1024 * 1024, wm1, wv1, W1t, 1024, 1024, 1024);
    gemm_bt_relu<<<dim3(8, 8, SC), 256, 0, stream>>>(
        act1, (size_t)1024 * 1024, 1024, W1t, act2, 1024, bm1, bv1, be1, s0);
    // last layer
    sample_wl_k<<<SC * 64, 256, 0, stream>>>(
        wel + (size_t)s0 * 1024 * 10, wlm, wlv, Wlt);
    gemm_last_k<<<dim3(16, SC), 256, 0, stream>>>(
        act2, Wlt, out, blm, blv, bel, s0);
  }
}